// Round 9
// baseline (146.506 us; speedup 1.0000x reference)
//
#include <hip/hip_runtime.h>
#include <float.h>
#include <math.h>

// ---------------------------------------------------------------------------
// DRR via Siddon ray casting.  NX=NY=NZ=192, H=W=192, SDR=300, DELX=DELY=2,
// SPACING=1, BAM=1, B=2, N_SUB=18432.
// Graph (4 nodes): memset(out) -> reduce (block partials) -> setup (final
// fold + LDS mark + TWO tile-ordered lists) -> ray (float gathers, per-batch
// adaptive lane mapping, XCD swizzle, A/B pipelined Siddon).
//
// Perf history:
//   r1/r4: same-cache-line atomics (~12ns each) -> two-stage reduction (r5).
//   r3 FAIL: incremental alpha drift + linear-addr clamp; voxel must be
//     recomputed from the segment midpoint every step.
//   r6: node fusion NEUTRAL.  r7: fp16+XCD swizzle cut FETCH 85->20MB,
//     time flat -> not BW-bound.  r8: A/B pipeline NEUTRAL at 48% occupancy
//     -> not latency-bound either.  Diagnosis: TA-bound (unique cache lines
//     per 64-lane gather).  r9: revert lean r5 pipeline + shape the gather
//     front: 16-lane runs along whichever detector axis has the larger
//     volume-z (stride-1) component, chosen per batch at runtime.
// ---------------------------------------------------------------------------

#define NDIM   192
#define HW     (NDIM * NDIM)          // 36864
#define NSUB   (HW / 2)               // 18432
#define NTILE  576                    // 64-pixel tiles (4x16 or 16x4)
#define NBATCH 2
#define NCHUNK 16
#define NVOX   (NDIM * NDIM * NDIM)   // 7077888
#define SDRF   300.0f
#define RBLK   1728                   // 1728*256*4 float4 == NVOX/4

// ws layout (bytes):
//   [0..12)           final {smin, rmin, rmax}
//   [16 .. +73728)    listA (4x16 tiles: 16 lanes along pj)
//   [.. +73728)       listB (16x4 tiles: 16 lanes along pi)
//   [.. +4*3*RBLK)    block partials smin/rmin/rmax
#define WS_LISTA_OFF 16
#define WS_LISTB_OFF (WS_LISTA_OFF + 4 * NSUB)
#define WS_PART_OFF  (WS_LISTB_OFF + 4 * NSUB)

// --------------------------- reduction stage 1 -----------------------------
// soft_min over (-800, 350]; rmin/rmax over v > -800 (BAM==1 -> identity).
__global__ __launch_bounds__(256) void reduce_kernel(
    const float* __restrict__ vol, float* __restrict__ parts) {
    const int tid = blockIdx.x * 256 + threadIdx.x;
    const float4* __restrict__ v4 = (const float4*)vol;
    const int S = RBLK * 256;         // 442368

    float4 r0 = v4[tid + 0 * S];
    float4 r1 = v4[tid + 1 * S];
    float4 r2 = v4[tid + 2 * S];
    float4 r3 = v4[tid + 3 * S];

    float smin = FLT_MAX, rmin = FLT_MAX, rmax = -FLT_MAX;
    float4 rr[4] = {r0, r1, r2, r3};
#pragma unroll
    for (int k = 0; k < 4; ++k) {
        float xs[4] = {rr[k].x, rr[k].y, rr[k].z, rr[k].w};
#pragma unroll
        for (int j = 0; j < 4; ++j) {
            float x = xs[j];
            bool in = (x > -800.0f);
            rmin = fminf(rmin, in ? x : FLT_MAX);
            rmax = fmaxf(rmax, in ? x : -FLT_MAX);
            smin = fminf(smin, (in && x <= 350.0f) ? x : FLT_MAX);
        }
    }
#pragma unroll
    for (int off = 32; off > 0; off >>= 1) {
        smin = fminf(smin, __shfl_down(smin, off));
        rmin = fminf(rmin, __shfl_down(rmin, off));
        rmax = fmaxf(rmax, __shfl_down(rmax, off));
    }
    __shared__ float sm[4], rm[4], rx[4];
    int w = threadIdx.x >> 6;
    if ((threadIdx.x & 63) == 0) { sm[w] = smin; rm[w] = rmin; rx[w] = rmax; }
    __syncthreads();
    if (threadIdx.x == 0) {
        parts[blockIdx.x] =
            fminf(fminf(sm[0], sm[1]), fminf(sm[2], sm[3]));
        parts[RBLK + blockIdx.x] =
            fminf(fminf(rm[0], rm[1]), fminf(rm[2], rm[3]));
        parts[2 * RBLK + blockIdx.x] =
            fmaxf(fmaxf(rx[0], rx[1]), fmaxf(rx[2], rx[3]));
    }
}

// --------------------------- lane mappings ---------------------------------
// Mode A: tiles 4(pi) x 16(pj); lane runs along pj (detector x).
// Mode B: tiles 16(pi) x 4(pj); lane runs along pi (detector y).
__device__ __forceinline__ int keyA(int tile, int lane) {
    int pi = (tile / 12) * 4 + (lane >> 4);
    int pj = (tile % 12) * 16 + (lane & 15);
    return pi * NDIM + pj;
}
__device__ __forceinline__ int keyB(int tile, int lane) {
    int pi = (tile / 48) * 16 + (lane & 15);
    int pj = (tile % 48) * 4 + (lane >> 4);
    return pi * NDIM + pj;
}

// --------------------------- fused setup -----------------------------------
// Single block, 1024 threads: (a) fold partials -> ws[0..2]; (b) LDS mark;
// (c) per-tile count -> scan -> compact list, done for BOTH lane mappings.
__global__ __launch_bounds__(1024) void setup_kernel(
    const float* __restrict__ parts, const int* __restrict__ sidx,
    float* __restrict__ wsf, int* __restrict__ listA,
    int* __restrict__ listB) {
    __shared__ unsigned char smark[HW];   // 36 KB
    __shared__ int s[NTILE];
    __shared__ float sm[16], rm[16], rx[16];
    const int t = threadIdx.x;

    int4* sm4 = (int4*)smark;
    for (int i = t; i < HW / 16; i += 1024) sm4[i] = make_int4(0, 0, 0, 0);

    float smin = FLT_MAX, rmin = FLT_MAX, rmax = -FLT_MAX;
    for (int i = t; i < RBLK; i += 1024) {
        smin = fminf(smin, parts[i]);
        rmin = fminf(rmin, parts[RBLK + i]);
        rmax = fmaxf(rmax, parts[2 * RBLK + i]);
    }
#pragma unroll
    for (int off = 32; off > 0; off >>= 1) {
        smin = fminf(smin, __shfl_down(smin, off));
        rmin = fminf(rmin, __shfl_down(rmin, off));
        rmax = fmaxf(rmax, __shfl_down(rmax, off));
    }
    int w = t >> 6;
    if ((t & 63) == 0) { sm[w] = smin; rm[w] = rmin; rx[w] = rmax; }
    __syncthreads();

    for (int i = t; i < NSUB; i += 1024) smark[sidx[i]] = 1;
    if (t == 0) {
        float a = FLT_MAX, b = FLT_MAX, c = -FLT_MAX;
#pragma unroll
        for (int k = 0; k < 16; ++k) {
            a = fminf(a, sm[k]); b = fminf(b, rm[k]); c = fmaxf(c, rx[k]);
        }
        wsf[0] = a; wsf[1] = b; wsf[2] = c;
    }
    __syncthreads();

    // ---- mode A ----
    int cnt = 0;
    if (t < NTILE) {
#pragma unroll 8
        for (int lane = 0; lane < 64; ++lane) cnt += smark[keyA(t, lane)];
        s[t] = cnt;
    }
    __syncthreads();
    for (int off = 1; off < NTILE; off <<= 1) {
        int v = 0, u = 0;
        if (t < NTILE) { v = s[t]; u = (t >= off) ? s[t - off] : 0; }
        __syncthreads();
        if (t < NTILE) s[t] = v + u;
        __syncthreads();
    }
    if (t < NTILE) {
        int pos = s[t] - cnt;
        for (int lane = 0; lane < 64; ++lane) {
            int p = keyA(t, lane);
            if (smark[p]) listA[pos++] = p;
        }
    }
    __syncthreads();

    // ---- mode B ----
    cnt = 0;
    if (t < NTILE) {
#pragma unroll 8
        for (int lane = 0; lane < 64; ++lane) cnt += smark[keyB(t, lane)];
        s[t] = cnt;
    }
    __syncthreads();
    for (int off = 1; off < NTILE; off <<= 1) {
        int v = 0, u = 0;
        if (t < NTILE) { v = s[t]; u = (t >= off) ? s[t - off] : 0; }
        __syncthreads();
        if (t < NTILE) s[t] = v + u;
        __syncthreads();
    }
    if (t < NTILE) {
        int pos = s[t] - cnt;
        for (int lane = 0; lane < 64; ++lane) {
            int p = keyB(t, lane);
            if (smark[p]) listB[pos++] = p;
        }
    }
}

// --------------------------- axis iterator init ----------------------------
__device__ __forceinline__ void init_axis(float s, float d, float a_lo,
                                          int& i, int& st, float& na) {
    if (d > 0.0f) {
        st = 1;
        float f = s + a_lo * d;
        int ii = (int)floorf(f) + 1;
        ii = max(0, min(ii, NDIM + 1));
        while (ii <= NDIM && ((float)ii - s) / d <= a_lo) ++ii;
        while (ii > 0 && ((float)(ii - 1) - s) / d > a_lo) --ii;
        i  = ii;
        na = (ii <= NDIM) ? ((float)ii - s) / d : FLT_MAX;
    } else {
        st = -1;
        float f = s + a_lo * d;
        int ii = (int)ceilf(f) - 1;
        ii = max(-1, min(ii, NDIM));
        while (ii >= 0 && ((float)ii - s) / d <= a_lo) --ii;
        while (ii < NDIM && ((float)(ii + 1) - s) / d > a_lo) ++ii;
        i  = ii;
        na = (ii >= 0) ? ((float)ii - s) / d : FLT_MAX;
    }
}

// --------------------------- ray kernel ------------------------------------
// 1-D grid, 2304 blocks, XCD-swizzled (bid&7 -> XCD; each XCD owns one batch
// + one quarter-detector band x all 16 chunks).  Wave = 64 consecutive list
// entries; the list ORDER is chosen per batch so the 16-lane runs walk the
// volume's stride-1 (z) axis as closely as the orientation allows.
// Inner loop: A/B pipelined Siddon; voxel recomputed from segment midpoint
// (reference-exact); alpha crossings via reciprocal-mul from integer index.
__global__ __launch_bounds__(256) void ray_kernel(
    const float* __restrict__ vol, const float* __restrict__ rot,
    const float* __restrict__ trans, const float* __restrict__ wsc,
    const int* __restrict__ listA, const int* __restrict__ listB,
    float* __restrict__ out) {
    const int bid = blockIdx.x;
    const int xcd  = bid & 7;
    const int s_   = bid >> 3;            // 0..287
    const int b    = xcd >> 2;            // batch
    const int xr   = xcd & 3;             // quarter-detector region
    const int c    = s_ & 15;             // alpha chunk
    const int pblk = s_ >> 4;             // 0..17
    const int n = (xr * 18 + pblk) * 256 + threadIdx.x;

    // density normalization constants
    float smin = wsc[0];
    float dmin = fminf(smin, wsc[1]);
    float scale = 1.0f / (fmaxf(smin, wsc[2]) - dmin);

    // rotation R = Rz(r0) @ Ry(r1) @ Rx(r2)
    float rz = rot[b * 3 + 0], ry = rot[b * 3 + 1], rx = rot[b * 3 + 2];
    float cz = cosf(rz), sz = sinf(rz);
    float cy = cosf(ry), sy = sinf(ry);
    float cx = cosf(rx), sx = sinf(rx);
    float R00 = cz * cy;
    float R01 = cz * sy * sx - sz * cx;
    float R02 = sz * sx + cz * sy * cx;
    float R10 = sz * cy;
    float R11 = cz * cx + sz * sy * sx;
    float R12 = sz * sy * cx - cz * sx;
    float R20 = -sy;
    float R21 = cy * sx;
    float R22 = cy * cx;

    // adaptive lane mapping: pj-runs (listA) need |R20| (detector-x z-comp);
    // pi-runs (listB) need |R21|.
    const int* __restrict__ list = (fabsf(R20) >= fabsf(R21)) ? listA : listB;
    const int p  = list[n];
    const int pi = p / NDIM;
    const int pj = p % NDIM;

    float tx = trans[b * 3 + 0] + 96.0f;
    float ty = trans[b * 3 + 1] + 96.0f;
    float tz = trans[b * 3 + 2] + 96.0f;

    float srcx = R02 * SDRF + tx;
    float srcy = R12 * SDRF + ty;
    float srcz = R22 * SDRF + tz;
    float gx = ((float)pj - 95.5f) * 2.0f;
    float gy = ((float)pi - 95.5f) * 2.0f;
    float tgx = R00 * gx + R01 * gy + R02 * (-SDRF) + tx;
    float tgy = R10 * gx + R11 * gy + R12 * (-SDRF) + ty;
    float tgz = R20 * gx + R21 * gy + R22 * (-SDRF) + tz;

    float sdx = tgx - srcx, sdy = tgy - srcy, sdz = tgz - srcz;
    float dsx = (sdx == 0.0f) ? 1e-9f : sdx;
    float dsy = (sdy == 0.0f) ? 1e-9f : sdy;
    float dsz = (sdz == 0.0f) ? 1e-9f : sdz;

    float af0 = (0.0f - srcx) / dsx, al0 = (192.0f - srcx) / dsx;
    float af1 = (0.0f - srcy) / dsy, al1 = (192.0f - srcy) / dsy;
    float af2 = (0.0f - srcz) / dsz, al2 = (192.0f - srcz) / dsz;
    float amin = fmaxf(fmaxf(fminf(af0, al0), fminf(af1, al1)), fminf(af2, al2));
    amin = fmaxf(amin, 0.0f);
    float amax = fminf(fminf(fmaxf(af0, al0), fmaxf(af1, al1)), fmaxf(af2, al2));
    amax = fminf(amax, 1.0f);
    amax = fmaxf(amax, amin);
    float ray_len = sqrtf(sdx * sdx + sdy * sdy + sdz * sdz);

    float span = amax - amin;
    float a_lo = amin + span * ((float)c / (float)NCHUNK);
    float a_hi = (c == NCHUNK - 1) ? amax
                                   : amin + span * ((float)(c + 1) / (float)NCHUNK);

    int i0, i1, i2, st0, st1, st2;
    float na0, na1, na2;
    init_axis(srcx, dsx, a_lo, i0, st0, na0);
    init_axis(srcy, dsy, a_lo, i1, st1, na1);
    init_axis(srcz, dsz, a_lo, i2, st2, na2);

    float r0 = 1.0f / dsx, r1 = 1.0f / dsy, r2 = 1.0f / dsz;
    float fi0 = (float)i0, fi1 = (float)i1, fi2 = (float)i2;
    float fs0 = (float)st0, fs1 = (float)st1, fs2 = (float)st2;

    float cur = a_lo;
    float acc = 0.0f;                 // sum of step * raw density

    auto compute_seg = [&](float& step, bool& fin, float& v) {
        float an = fminf(fminf(na0, na1), na2);
        fin = !(an < a_hi);
        float a2 = fin ? a_hi : an;
        float mid = 0.5f * (cur + a2);
        float px = fmaf(mid, sdx, srcx);
        float py = fmaf(mid, sdy, srcy);
        float pz = fmaf(mid, sdz, srcz);
        // truncation == floor after the >=0 clamp (reference clips to [0,191])
        int ix = min(max((int)px, 0), NDIM - 1);
        int iy = min(max((int)py, 0), NDIM - 1);
        int iz = min(max((int)pz, 0), NDIM - 1);
        v = vol[(NDIM - 1) * HW - ix * HW + iy * NDIM + iz];  // flip axis 0
        bool c0 = (na0 == an), c1 = (na1 == an), c2 = (na2 == an);
        float nf0 = fi0 + fs0, nf1 = fi1 + fs1, nf2 = fi2 + fs2;
        float nn0 = (nf0 - srcx) * r0;
        float nn1 = (nf1 - srcy) * r1;
        float nn2 = (nf2 - srcz) * r2;
        fi0 = c0 ? nf0 : fi0;  na0 = c0 ? nn0 : na0;
        fi1 = c1 ? nf1 : fi1;  na1 = c1 ? nn1 : na1;
        fi2 = c2 ? nf2 : fi2;  na2 = c2 ? nn2 : na2;
        step = a2 - cur;
        cur = a2;
    };
    auto consume = [&](float step, float v) {
        float dv = (v <= -800.0f) ? smin : v;
        acc = fmaf(step, dv, acc);
    };

    float stepA, stepB, vA, vB;
    bool  finA,  finB;
    compute_seg(stepA, finA, vA);
    while (true) {
        if (finA) { consume(stepA, vA); break; }
        compute_seg(stepB, finB, vB);    // load B in flight
        consume(stepA, vA);              // wait at vmcnt(1)
        if (finB) { consume(stepB, vB); break; }
        compute_seg(stepA, finA, vA);    // load A in flight
        consume(stepB, vB);              // wait at vmcnt(1)
    }
    // sum step*(dv - dmin)*scale == scale*(acc - dmin*(a_hi - a_lo))
    float res = (acc - dmin * (a_hi - a_lo)) * scale * ray_len;
    atomicAdd(&out[b * HW + p], res);
}

// --------------------------- launch ----------------------------------------
extern "C" void kernel_launch(void* const* d_in, const int* in_sizes, int n_in,
                              void* d_out, int out_size, void* d_ws,
                              size_t ws_size, hipStream_t stream) {
    const float* vol   = (const float*)d_in[0];
    const float* rot   = (const float*)d_in[1];
    const float* trans = (const float*)d_in[2];
    const int*   sidx  = (const int*)d_in[3];
    float* out = (float*)d_out;

    float* wsf   = (float*)d_ws;
    int*   listA = (int*)((unsigned char*)d_ws + WS_LISTA_OFF);
    int*   listB = (int*)((unsigned char*)d_ws + WS_LISTB_OFF);
    float* parts = (float*)((unsigned char*)d_ws + WS_PART_OFF);

    hipMemsetAsync(d_out, 0, (size_t)out_size * sizeof(float), stream);
    reduce_kernel<<<RBLK, 256, 0, stream>>>(vol, parts);
    setup_kernel<<<1, 1024, 0, stream>>>(parts, sidx, wsf, listA, listB);
    ray_kernel<<<NCHUNK * NBATCH * (NSUB / 256), 256, 0, stream>>>(
        vol, rot, trans, wsf, listA, listB, out);
}

// Round 10
// 131.024 us; speedup vs baseline: 1.1182x; 1.1182x over previous
//
#include <hip/hip_runtime.h>
#include <hip/hip_fp16.h>
#include <float.h>
#include <math.h>

// ---------------------------------------------------------------------------
// DRR via Siddon ray casting.  NX=NY=NZ=192, H=W=192, SDR=300, DELX=DELY=2,
// SPACING=1, BAM=1, B=2, N_SUB=18432.
// Graph (5 nodes): memset(out) -> reduce (block partials) -> setup (final
// fold + LDS mark + tile-ordered list) -> densify (fp16 BRICKED volume) ->
// ray (bricked-half gathers, XCD swizzle, A/B pipelined Siddon).
//
// BRICK LAYOUT: one 64B cache line = 4(x) x 4(y) x 2(z) voxel bricklet.
//   addr(ix,iy,iz) = (((ix>>2)*48 + (iy>>2))*96 + (iz>>1))*32
//                  + (ix&3)*8 + (iy&3)*2 + (iz&1)
// Rationale: r7 (fp16, -4x bytes), r8 (A/B pipeline), r9 (lane orientation)
// all left ray at ~46-50us, VALUBusy ~37%, HBM ~10%.  The invariant cost is
// UNIQUE CACHE LINES PER 64-LANE GATHER (~40-60 with row-major: every
// (ix,iy) pair is its own line).  A 3D-compact line cuts that to ~9-16
// independent of ray orientation.
//
// Perf history:
//   r1/r4: same-cache-line atomics (~12ns each) -> two-stage reduction (r5).
//   r3 FAIL: incremental alpha drift; voxel must be recomputed from the
//     segment midpoint every step (bit-exact vs reference).
//   r6: node fusion NEUTRAL.  r7: fp16 cut FETCH 85->20MB, time flat.
//   r8: A/B pipeline NEUTRAL.  r9: lane orientation NEUTRAL/regressed.
// ---------------------------------------------------------------------------

#define NDIM   192
#define HW     (NDIM * NDIM)          // 36864
#define NSUB   (HW / 2)               // 18432
#define NTILE  576                    // 8x8 detector tiles
#define NBATCH 2
#define NCHUNK 16
#define NVOX   (NDIM * NDIM * NDIM)   // 7077888
#define SDRF   300.0f
#define RBLK   1728                   // 1728*256*4 float4 == NVOX/4
#define NLINE  (NVOX / 32)            // 221184 bricklet lines

// ws layout (bytes):
//   [0..12)         final {smin, rmin, rmax}
//   [16..16+73728)  list (tile-ordered selected pixels)
//   [73744..94480)  block partials smin/rmin/rmax [RBLK each]
//   [98304..+14.2M) fp16 density volume, BRICKED layout (flip folded in)
#define WS_LIST_OFF 16
#define WS_PART_OFF (16 + 4 * NSUB)
#define WS_DENS_OFF 98304

// --------------------------- reduction stage 1 -----------------------------
// soft_min over (-800, 350]; rmin/rmax over v > -800 (BAM==1 -> identity).
__global__ __launch_bounds__(256) void reduce_kernel(
    const float* __restrict__ vol, float* __restrict__ parts) {
    const int tid = blockIdx.x * 256 + threadIdx.x;
    const float4* __restrict__ v4 = (const float4*)vol;
    const int S = RBLK * 256;         // 442368

    float4 r0 = v4[tid + 0 * S];
    float4 r1 = v4[tid + 1 * S];
    float4 r2 = v4[tid + 2 * S];
    float4 r3 = v4[tid + 3 * S];

    float smin = FLT_MAX, rmin = FLT_MAX, rmax = -FLT_MAX;
    float4 rr[4] = {r0, r1, r2, r3};
#pragma unroll
    for (int k = 0; k < 4; ++k) {
        float xs[4] = {rr[k].x, rr[k].y, rr[k].z, rr[k].w};
#pragma unroll
        for (int j = 0; j < 4; ++j) {
            float x = xs[j];
            bool in = (x > -800.0f);
            rmin = fminf(rmin, in ? x : FLT_MAX);
            rmax = fmaxf(rmax, in ? x : -FLT_MAX);
            smin = fminf(smin, (in && x <= 350.0f) ? x : FLT_MAX);
        }
    }
#pragma unroll
    for (int off = 32; off > 0; off >>= 1) {
        smin = fminf(smin, __shfl_down(smin, off));
        rmin = fminf(rmin, __shfl_down(rmin, off));
        rmax = fmaxf(rmax, __shfl_down(rmax, off));
    }
    __shared__ float sm[4], rm[4], rx[4];
    int w = threadIdx.x >> 6;
    if ((threadIdx.x & 63) == 0) { sm[w] = smin; rm[w] = rmin; rx[w] = rmax; }
    __syncthreads();
    if (threadIdx.x == 0) {
        parts[blockIdx.x] =
            fminf(fminf(sm[0], sm[1]), fminf(sm[2], sm[3]));
        parts[RBLK + blockIdx.x] =
            fminf(fminf(rm[0], rm[1]), fminf(rm[2], rm[3]));
        parts[2 * RBLK + blockIdx.x] =
            fmaxf(fmaxf(rx[0], rx[1]), fmaxf(rx[2], rx[3]));
    }
}

// --------------------------- fused setup -----------------------------------
// Single block, 1024 threads: (a) fold partials -> ws[0..2]; (b) LDS mark;
// (c) per-8x8-tile count -> scan -> tile-ordered compact list.
__device__ __forceinline__ int key_to_pixel(int tile, int lane) {
    int pi = (tile / 24) * 8 + (lane >> 3);
    int pj = (tile % 24) * 8 + (lane & 7);
    return pi * NDIM + pj;
}

__global__ __launch_bounds__(1024) void setup_kernel(
    const float* __restrict__ parts, const int* __restrict__ sidx,
    float* __restrict__ wsf, int* __restrict__ list) {
    __shared__ unsigned char smark[HW];   // 36 KB
    __shared__ int s[NTILE];
    __shared__ float sm[16], rm[16], rx[16];
    const int t = threadIdx.x;

    int4* sm4 = (int4*)smark;
    for (int i = t; i < HW / 16; i += 1024) sm4[i] = make_int4(0, 0, 0, 0);

    float smin = FLT_MAX, rmin = FLT_MAX, rmax = -FLT_MAX;
    for (int i = t; i < RBLK; i += 1024) {
        smin = fminf(smin, parts[i]);
        rmin = fminf(rmin, parts[RBLK + i]);
        rmax = fmaxf(rmax, parts[2 * RBLK + i]);
    }
#pragma unroll
    for (int off = 32; off > 0; off >>= 1) {
        smin = fminf(smin, __shfl_down(smin, off));
        rmin = fminf(rmin, __shfl_down(rmin, off));
        rmax = fmaxf(rmax, __shfl_down(rmax, off));
    }
    int w = t >> 6;
    if ((t & 63) == 0) { sm[w] = smin; rm[w] = rmin; rx[w] = rmax; }
    __syncthreads();

    for (int i = t; i < NSUB; i += 1024) smark[sidx[i]] = 1;
    if (t == 0) {
        float a = FLT_MAX, b = FLT_MAX, c = -FLT_MAX;
#pragma unroll
        for (int k = 0; k < 16; ++k) {
            a = fminf(a, sm[k]); b = fminf(b, rm[k]); c = fmaxf(c, rx[k]);
        }
        wsf[0] = a; wsf[1] = b; wsf[2] = c;
    }
    __syncthreads();

    int cnt = 0;
    if (t < NTILE) {
#pragma unroll 8
        for (int lane = 0; lane < 64; ++lane)
            cnt += smark[key_to_pixel(t, lane)];
        s[t] = cnt;
    }
    __syncthreads();
    for (int off = 1; off < NTILE; off <<= 1) {
        int v = 0, u = 0;
        if (t < NTILE) {
            v = s[t];
            u = (t >= off) ? s[t - off] : 0;
        }
        __syncthreads();
        if (t < NTILE) s[t] = v + u;
        __syncthreads();
    }
    if (t < NTILE) {
        int pos = s[t] - cnt;
        for (int lane = 0; lane < 64; ++lane) {
            int p = key_to_pixel(t, lane);
            if (smark[p]) list[pos++] = p;
        }
    }
}

// --------------------------- densify (bricked) -----------------------------
// One thread produces one 64B output line = 4x4x2 voxel bricklet.
// line id g: col = g/96 (col = IX*48+IY), lin = g%96, base_z = lin*2.
// Within-line voxel w: ix = IX*4+(w>>3), iy = IY*4+((w>>1)&3), iz=base_z+(w&1)
// density(ix,iy,iz) = norm(vol[191-ix][iy][iz])  (flip folded in).
__global__ __launch_bounds__(256) void densify_kernel(
    const float* __restrict__ vol, const float* __restrict__ wsf,
    __half* __restrict__ dens) {
    const int g = blockIdx.x * 256 + threadIdx.x;    // 0..NLINE-1
    const int col = g / 96;
    const int lin = g - col * 96;
    const int IX = col / 48;
    const int IY = col - IX * 48;
    const int base_z = lin * 2;

    float smin = wsf[0];
    float dmin = fminf(smin, wsf[1]);
    float scale = 1.0f / (fmaxf(smin, wsf[2]) - dmin);

    union { __half h[32]; int4 q[4]; } u;
#pragma unroll
    for (int r = 0; r < 16; ++r) {            // r = ixl*4 + iyl
        int ixl = r >> 2, iyl = r & 3;
        int ix = IX * 4 + ixl;
        int iy = IY * 4 + iyl;
        const float2 v2 = *(const float2*)(vol + (NDIM - 1 - ix) * HW
                                               + iy * NDIM + base_z);
        float d0 = (v2.x <= -800.0f) ? smin : v2.x;
        float d1 = (v2.y <= -800.0f) ? smin : v2.y;
        u.h[(r << 1) + 0] = __float2half_rn((d0 - dmin) * scale);
        u.h[(r << 1) + 1] = __float2half_rn((d1 - dmin) * scale);
    }
    int4* d4 = (int4*)(dens + g * 32);
    d4[0] = u.q[0]; d4[1] = u.q[1]; d4[2] = u.q[2]; d4[3] = u.q[3];
}

// --------------------------- axis iterator init ----------------------------
__device__ __forceinline__ void init_axis(float s, float d, float a_lo,
                                          int& i, int& st, float& na) {
    if (d > 0.0f) {
        st = 1;
        float f = s + a_lo * d;
        int ii = (int)floorf(f) + 1;
        ii = max(0, min(ii, NDIM + 1));
        while (ii <= NDIM && ((float)ii - s) / d <= a_lo) ++ii;
        while (ii > 0 && ((float)(ii - 1) - s) / d > a_lo) --ii;
        i  = ii;
        na = (ii <= NDIM) ? ((float)ii - s) / d : FLT_MAX;
    } else {
        st = -1;
        float f = s + a_lo * d;
        int ii = (int)ceilf(f) - 1;
        ii = max(-1, min(ii, NDIM));
        while (ii >= 0 && ((float)ii - s) / d <= a_lo) --ii;
        while (ii < NDIM && ((float)(ii + 1) - s) / d > a_lo) ++ii;
        i  = ii;
        na = (ii >= 0) ? ((float)ii - s) / d : FLT_MAX;
    }
}

// --------------------------- ray kernel ------------------------------------
// 1-D grid of 2304 blocks, XCD-swizzled (bid&7 -> XCD; each XCD gets one
// batch + one quarter-detector band x all 16 chunks).  Wave = 64 consecutive
// tile-ordered list entries (8x8 detector patch).  A/B pipelined Siddon;
// voxel recomputed from segment midpoint (reference-exact); gathers hit the
// BRICKED fp16 volume (3D-compact cache lines).
__global__ __launch_bounds__(256) void ray_kernel(
    const __half* __restrict__ dens, const float* __restrict__ rot,
    const float* __restrict__ trans, const int* __restrict__ list,
    float* __restrict__ out) {
    const int bid = blockIdx.x;
    const int xcd  = bid & 7;
    const int s_   = bid >> 3;            // 0..287
    const int b    = xcd >> 2;            // batch
    const int xr   = xcd & 3;             // quarter-detector region
    const int c    = s_ & 15;             // alpha chunk
    const int pblk = s_ >> 4;             // 0..17
    const int n = (xr * 18 + pblk) * 256 + threadIdx.x;

    const int p  = list[n];
    const int pi = p / NDIM;
    const int pj = p % NDIM;

    // rotation R = Rz(r0) @ Ry(r1) @ Rx(r2)
    float rz = rot[b * 3 + 0], ry = rot[b * 3 + 1], rx = rot[b * 3 + 2];
    float cz = cosf(rz), sz = sinf(rz);
    float cy = cosf(ry), sy = sinf(ry);
    float cx = cosf(rx), sx = sinf(rx);
    float R00 = cz * cy;
    float R01 = cz * sy * sx - sz * cx;
    float R02 = sz * sx + cz * sy * cx;
    float R10 = sz * cy;
    float R11 = cz * cx + sz * sy * sx;
    float R12 = sz * sy * cx - cz * sx;
    float R20 = -sy;
    float R21 = cy * sx;
    float R22 = cy * cx;
    float tx = trans[b * 3 + 0] + 96.0f;
    float ty = trans[b * 3 + 1] + 96.0f;
    float tz = trans[b * 3 + 2] + 96.0f;

    float srcx = R02 * SDRF + tx;
    float srcy = R12 * SDRF + ty;
    float srcz = R22 * SDRF + tz;
    float gx = ((float)pj - 95.5f) * 2.0f;
    float gy = ((float)pi - 95.5f) * 2.0f;
    float tgx = R00 * gx + R01 * gy + R02 * (-SDRF) + tx;
    float tgy = R10 * gx + R11 * gy + R12 * (-SDRF) + ty;
    float tgz = R20 * gx + R21 * gy + R22 * (-SDRF) + tz;

    float sdx = tgx - srcx, sdy = tgy - srcy, sdz = tgz - srcz;
    float dsx = (sdx == 0.0f) ? 1e-9f : sdx;
    float dsy = (sdy == 0.0f) ? 1e-9f : sdy;
    float dsz = (sdz == 0.0f) ? 1e-9f : sdz;

    float af0 = (0.0f - srcx) / dsx, al0 = (192.0f - srcx) / dsx;
    float af1 = (0.0f - srcy) / dsy, al1 = (192.0f - srcy) / dsy;
    float af2 = (0.0f - srcz) / dsz, al2 = (192.0f - srcz) / dsz;
    float amin = fmaxf(fmaxf(fminf(af0, al0), fminf(af1, al1)), fminf(af2, al2));
    amin = fmaxf(amin, 0.0f);
    float amax = fminf(fminf(fmaxf(af0, al0), fmaxf(af1, al1)), fmaxf(af2, al2));
    amax = fminf(amax, 1.0f);
    amax = fmaxf(amax, amin);
    float ray_len = sqrtf(sdx * sdx + sdy * sdy + sdz * sdz);

    float span = amax - amin;
    float a_lo = amin + span * ((float)c / (float)NCHUNK);
    float a_hi = (c == NCHUNK - 1) ? amax
                                   : amin + span * ((float)(c + 1) / (float)NCHUNK);

    int i0, i1, i2, st0, st1, st2;
    float na0, na1, na2;
    init_axis(srcx, dsx, a_lo, i0, st0, na0);
    init_axis(srcy, dsy, a_lo, i1, st1, na1);
    init_axis(srcz, dsz, a_lo, i2, st2, na2);

    float r0 = 1.0f / dsx, r1 = 1.0f / dsy, r2 = 1.0f / dsz;
    float fi0 = (float)i0, fi1 = (float)i1, fi2 = (float)i2;
    float fs0 = (float)st0, fs1 = (float)st1, fs2 = (float)st2;

    float cur = a_lo;
    float acc = 0.0f;                 // sum of step * normalized density

    // One Siddon segment: crossing, midpoint voxel (reference-exact), ISSUE
    // the bricked gather, advance alpha state.  Consume one stage later.
    auto compute_seg = [&](float& step, bool& fin, __half& hv) {
        float an = fminf(fminf(na0, na1), na2);
        fin = !(an < a_hi);
        float a2 = fin ? a_hi : an;
        float mid = 0.5f * (cur + a2);
        float px = fmaf(mid, sdx, srcx);
        float py = fmaf(mid, sdy, srcy);
        float pz = fmaf(mid, sdz, srcz);
        // truncation == floor after the >=0 clamp (reference clips to [0,191])
        int ix = min(max((int)px, 0), NDIM - 1);
        int iy = min(max((int)py, 0), NDIM - 1);
        int iz = min(max((int)pz, 0), NDIM - 1);
        // bricked address: 64B line = 4x4x2 voxels
        int addr = ((((ix >> 2) * 48 + (iy >> 2)) * 96 + (iz >> 1)) << 5)
                 + ((ix & 3) << 3) + ((iy & 3) << 1) + (iz & 1);
        hv = dens[addr];
        bool c0 = (na0 == an), c1 = (na1 == an), c2 = (na2 == an);
        float nf0 = fi0 + fs0, nf1 = fi1 + fs1, nf2 = fi2 + fs2;
        float nn0 = (nf0 - srcx) * r0;
        float nn1 = (nf1 - srcy) * r1;
        float nn2 = (nf2 - srcz) * r2;
        fi0 = c0 ? nf0 : fi0;  na0 = c0 ? nn0 : na0;
        fi1 = c1 ? nf1 : fi1;  na1 = c1 ? nn1 : na1;
        fi2 = c2 ? nf2 : fi2;  na2 = c2 ? nn2 : na2;
        step = a2 - cur;
        cur = a2;
    };

    float stepA, stepB;
    bool  finA,  finB;
    __half hvA, hvB;
    compute_seg(stepA, finA, hvA);
    while (true) {
        if (finA) { acc = fmaf(stepA, __half2float(hvA), acc); break; }
        compute_seg(stepB, finB, hvB);                 // load B in flight
        acc = fmaf(stepA, __half2float(hvA), acc);     // wait at vmcnt(1)
        if (finB) { acc = fmaf(stepB, __half2float(hvB), acc); break; }
        compute_seg(stepA, finA, hvA);                 // load A in flight
        acc = fmaf(stepB, __half2float(hvB), acc);     // wait at vmcnt(1)
    }
    atomicAdd(&out[b * HW + p], acc * ray_len);
}

// --------------------------- launch ----------------------------------------
extern "C" void kernel_launch(void* const* d_in, const int* in_sizes, int n_in,
                              void* d_out, int out_size, void* d_ws,
                              size_t ws_size, hipStream_t stream) {
    const float* vol   = (const float*)d_in[0];
    const float* rot   = (const float*)d_in[1];
    const float* trans = (const float*)d_in[2];
    const int*   sidx  = (const int*)d_in[3];
    float* out = (float*)d_out;

    float*  wsf   = (float*)d_ws;
    int*    list  = (int*)((unsigned char*)d_ws + WS_LIST_OFF);
    float*  parts = (float*)((unsigned char*)d_ws + WS_PART_OFF);
    __half* dens  = (__half*)((unsigned char*)d_ws + WS_DENS_OFF);

    hipMemsetAsync(d_out, 0, (size_t)out_size * sizeof(float), stream);
    reduce_kernel<<<RBLK, 256, 0, stream>>>(vol, parts);
    setup_kernel<<<1, 1024, 0, stream>>>(parts, sidx, wsf, list);
    densify_kernel<<<NLINE / 256, 256, 0, stream>>>(vol, wsf, dens);
    ray_kernel<<<NCHUNK * NBATCH * (NSUB / 256), 256, 0, stream>>>(
        dens, rot, trans, list, out);
}